// Round 1
// baseline (1688.666 us; speedup 1.0000x reference)
//
#include <hip/hip_runtime.h>
#include <hip/hip_bf16.h>
#include <math.h>

#define BB 16384      // B
#define CC 50         // C clusters
#define KK 128        // top-K
#define DD 128        // feature dim
#define MM 12800      // CC * 2 * KK rows of F
#define NSPLIT 5      // column splits for the fused sim kernel
#define CPS (MM / NSPLIT)   // 2560 columns per split
#define TM 64
#define TN 64
#define SCALE2 2.8853900817779268f   // 1/(TEMP*ln2) = 2/ln2 : exp(x/T) = exp2(x*SCALE2)

// ---------------------------------------------------------------------------
// Kernel 1: per-cluster top-K via 4-pass radix select on float bit patterns.
// prob >= 0 (uniform [0,1)) so uint bit pattern order == float order.
// Tie-break at the boundary: smallest indices among values == threshold
// (matches jax.lax.top_k stability). Output: the index SET (order arbitrary).
// ---------------------------------------------------------------------------
__global__ void topk_kernel(const float* __restrict__ prob, int* __restrict__ topk) {
  __shared__ int hist[256];
  __shared__ int sChosen, sKrem, gtc, eqc;
  __shared__ int eqIdx[256];
  const int c = blockIdx.x, t = threadIdx.x;
  unsigned prefix = 0;
  int k_rem = KK;

  for (int pass = 0; pass < 4; ++pass) {
    const int shift = 24 - pass * 8;
    hist[t] = 0;
    __syncthreads();
    for (int i = t; i < BB; i += 256) {
      unsigned u = __float_as_uint(prob[i * CC + c]);
      bool match = (pass == 0) || ((u >> (shift + 8)) == (prefix >> (shift + 8)));
      if (match) atomicAdd(&hist[(u >> shift) & 255], 1);
    }
    __syncthreads();
    if (t == 0) {
      int kr = k_rem, b = 255;
      for (; b > 0; --b) {
        if (kr > hist[b]) kr -= hist[b];
        else break;
      }
      sChosen = b; sKrem = kr;
    }
    __syncthreads();
    prefix |= ((unsigned)sChosen) << shift;
    k_rem = sKrem;
    __syncthreads();
  }

  const unsigned T = prefix;          // threshold value (bit pattern)
  if (t == 0) { gtc = 0; eqc = 0; }
  __syncthreads();
  for (int i = t; i < BB; i += 256) {
    unsigned u = __float_as_uint(prob[i * CC + c]);
    if (u > T) {
      int pos = atomicAdd(&gtc, 1);
      topk[c * KK + pos] = i;
    } else if (u == T) {
      int e = atomicAdd(&eqc, 1);
      if (e < 256) eqIdx[e] = i;
    }
  }
  __syncthreads();
  if (t == 0) {
    int base = gtc;                   // == KK - k_rem
    int ec = eqc < 256 ? eqc : 256;
    for (int j = 0; j < k_rem; ++j) { // take k_rem smallest indices among equals
      int bi = -1, bv = 0x7fffffff;
      for (int q = 0; q < ec; ++q) {
        int v = eqIdx[q];
        if (v >= 0 && v < bv) { bv = v; bi = q; }
      }
      topk[c * KK + base + j] = bv;
      eqIdx[bi] = -1;
    }
  }
}

// ---------------------------------------------------------------------------
// Kernel 2: gather selected rows and L2-normalize. One wave per output row.
// F[c*256 + p] = normalize( p<128 ? z_i[topk[c][p]] : z_j[topk[c][p-128]] )
// ---------------------------------------------------------------------------
__global__ void gather_norm(const float* __restrict__ zi, const float* __restrict__ zj,
                            const int* __restrict__ topk, float* __restrict__ F) {
  const int gw = (blockIdx.x * 256 + threadIdx.x) >> 6;   // global wave id = row
  const int lane = threadIdx.x & 63;
  if (gw >= MM) return;
  const int c = gw >> 8, p = gw & 255;
  const int idx = topk[c * KK + (p & (KK - 1))];
  const float* src = (p < KK ? zi : zj) + (size_t)idx * DD;
  float2 v = ((const float2*)src)[lane];
  float ss = fmaf(v.x, v.x, v.y * v.y);
#pragma unroll
  for (int m = 1; m < 64; m <<= 1) ss += __shfl_xor(ss, m, 64);
  const float scale = 1.0f / fmaxf(sqrtf(ss), 1e-8f);
  ((float2*)(F + (size_t)gw * DD))[lane] = make_float2(v.x * scale, v.y * scale);
}

// ---------------------------------------------------------------------------
// Kernel 3: fused  F·Fᵀ -> exp -> masked row sums.
// Block: 64 rows x 2560 cols (one split). LDS tiles are stored XOR-swizzled at
// float4 granularity: float4_idx(r,k4) = r*32 + (k4 ^ (r&31)).
//  - staging writes: lanes cover k4=0..31 for fixed r -> permutation -> conflict-free
//  - A reads (4 consecutive rows, fixed k4): distinct low-3-bits -> conflict-free
//  - B reads (16 rows stride 1, fixed k4): 2-way -> free (m136)
// Read address = base_r XOR (k4<<4), one v_xor per read (bits disjoint).
// ---------------------------------------------------------------------------
__global__ __launch_bounds__(256) void sim_kernel(const float* __restrict__ F,
                                                  float* __restrict__ part) {
  __shared__ float As[TM * DD];   // 32 KB
  __shared__ float Bs[TN * DD];   // 32 KB
  const int t = threadIdx.x;
  const int tx = t & 15, ty = t >> 4;
  const int rowBlk = blockIdx.x / NSPLIT;
  const int split  = blockIdx.x % NSPLIT;
  const int rowBase = rowBlk * TM;
  const int colBase = split * CPS;
  const int c0 = rowBase & ~255;            // own cluster's column block start

  // ---- stage A tile (swizzled) ----
  {
    const float4* src = (const float4*)(F + (size_t)rowBase * DD);
    char* dst = (char*)As;
#pragma unroll
    for (int i = 0; i < 8; ++i) {
      int f4 = t + 256 * i;
      int r = f4 >> 5, k4 = f4 & 31;
      *(float4*)(dst + r * 512 + ((k4 ^ (r & 31)) << 4)) = src[f4];
    }
  }

  // per-thread swizzle base offsets (bytes): r*512 + ((r&31)<<4)
  int aoff[4], boff[4];
#pragma unroll
  for (int ii = 0; ii < 4; ++ii) { int r = ty + 16 * ii; aoff[ii] = r * 512 + ((r & 31) << 4); }
#pragma unroll
  for (int jj = 0; jj < 4; ++jj) { int r = tx + 16 * jj; boff[jj] = r * 512 + ((r & 31) << 4); }

  float sAll[4] = {0, 0, 0, 0}, sOwn[4] = {0, 0, 0, 0}, sPos[4] = {0, 0, 0, 0};
  const char* Ab = (const char*)As;
  const char* Bb = (const char*)Bs;

  for (int tile = 0; tile < CPS / TN; ++tile) {
    const int colT = colBase + tile * TN;
    __syncthreads();                        // protect Bs from previous readers
    {
      const float4* src = (const float4*)(F + (size_t)colT * DD);
      char* dst = (char*)Bs;
#pragma unroll
      for (int i = 0; i < 8; ++i) {
        int f4 = t + 256 * i;
        int r = f4 >> 5, k4 = f4 & 31;
        *(float4*)(dst + r * 512 + ((k4 ^ (r & 31)) << 4)) = src[f4];
      }
    }
    __syncthreads();

    float acc[4][4] = {};
#pragma unroll
    for (int k4 = 0; k4 < 32; ++k4) {
      float4 a4[4], b4[4];
#pragma unroll
      for (int ii = 0; ii < 4; ++ii) a4[ii] = *(const float4*)(Ab + (aoff[ii] ^ (k4 << 4)));
#pragma unroll
      for (int jj = 0; jj < 4; ++jj) b4[jj] = *(const float4*)(Bb + (boff[jj] ^ (k4 << 4)));
#pragma unroll
      for (int ii = 0; ii < 4; ++ii)
#pragma unroll
        for (int jj = 0; jj < 4; ++jj) {
          acc[ii][jj] = fmaf(a4[ii].x, b4[jj].x, acc[ii][jj]);
          acc[ii][jj] = fmaf(a4[ii].y, b4[jj].y, acc[ii][jj]);
          acc[ii][jj] = fmaf(a4[ii].z, b4[jj].z, acc[ii][jj]);
          acc[ii][jj] = fmaf(a4[ii].w, b4[jj].w, acc[ii][jj]);
        }
    }

    // tile is 64-wide and own/pos boundaries are 128/256-aligned -> uniform per tile
    const bool tileOwn = (colT >= c0) && (colT < c0 + 256);
    const bool tilePos = tileOwn && (colT < c0 + 128);
#pragma unroll
    for (int ii = 0; ii < 4; ++ii) {
      float rs = 0.f;
#pragma unroll
      for (int jj = 0; jj < 4; ++jj) rs += exp2f(acc[ii][jj] * SCALE2);
      sAll[ii] += rs;
      if (tileOwn) sOwn[ii] += rs;
      if (tilePos) sPos[ii] += rs;
    }
  }

  // reduce across the 16 tx lanes (columns) within each 16-lane group
#pragma unroll
  for (int m = 1; m < 16; m <<= 1) {
#pragma unroll
    for (int ii = 0; ii < 4; ++ii) {
      sAll[ii] += __shfl_xor(sAll[ii], m, 16);
      sOwn[ii] += __shfl_xor(sOwn[ii], m, 16);
      sPos[ii] += __shfl_xor(sPos[ii], m, 16);
    }
  }
  if (tx == 0) {
#pragma unroll
    for (int ii = 0; ii < 4; ++ii) {
      int row = rowBase + ty + 16 * ii;
      float* pp = part + ((size_t)row * NSPLIT + split) * 4;
      pp[0] = sAll[ii]; pp[1] = sOwn[ii]; pp[2] = sPos[ii];
    }
  }
}

// ---------------------------------------------------------------------------
// Kernel 4: combine split partials -> per-row loss
// ---------------------------------------------------------------------------
__global__ void finalize_rows(const float* __restrict__ part, float* __restrict__ row_loss) {
  const int p = blockIdx.x * 256 + threadIdx.x;
  if (p >= MM) return;
  float a = 0.f, o = 0.f, q = 0.f;
#pragma unroll
  for (int s = 0; s < NSPLIT; ++s) {
    const float* pp = part + ((size_t)p * NSPLIT + s) * 4;
    a += pp[0]; o += pp[1]; q += pp[2];
  }
  row_loss[p] = logf(a - o) - logf(q);   // log(neg_sum) - log(pos_sum)
}

// ---------------------------------------------------------------------------
// Kernel 5: mean over 12800 rows -> scalar
// ---------------------------------------------------------------------------
__global__ void final_reduce(const float* __restrict__ row_loss, float* __restrict__ out) {
  __shared__ float red[16];
  const int t = threadIdx.x;                // 1024 threads
  float s = 0.f;
  for (int i = t; i < MM; i += 1024) s += row_loss[i];
#pragma unroll
  for (int m = 1; m < 64; m <<= 1) s += __shfl_xor(s, m, 64);
  if ((t & 63) == 0) red[t >> 6] = s;
  __syncthreads();
  if (t < 16) {
    float v = red[t];
#pragma unroll
    for (int m = 1; m < 16; m <<= 1) v += __shfl_xor(v, m, 16);
    if (t == 0) out[0] = v * (1.0f / MM);
  }
}

extern "C" void kernel_launch(void* const* d_in, const int* in_sizes, int n_in,
                              void* d_out, int out_size, void* d_ws, size_t ws_size,
                              hipStream_t stream) {
  const float* prob = (const float*)d_in[0];
  const float* zi   = (const float*)d_in[1];
  const float* zj   = (const float*)d_in[2];
  float* out = (float*)d_out;

  float* ws = (float*)d_ws;
  float* F        = ws;                                      // MM*DD        = 1,638,400 f
  int*   topk     = (int*)(ws + (size_t)MM * DD);            // CC*KK        =     6,400 i
  float* part     = ws + (size_t)MM * DD + CC * KK;          // MM*NSPLIT*4  =   256,000 f
  float* row_loss = part + (size_t)MM * NSPLIT * 4;          // MM           =    12,800 f

  topk_kernel  <<<CC, 256, 0, stream>>>(prob, topk);
  gather_norm  <<<MM / 4, 256, 0, stream>>>(zi, zj, topk, F);
  sim_kernel   <<<(MM / TM) * NSPLIT, 256, 0, stream>>>(F, part);
  finalize_rows<<<MM / 256, 256, 0, stream>>>(part, row_loss);
  final_reduce <<<1, 1024, 0, stream>>>(row_loss, out);
}

// Round 2
// 219.651 us; speedup vs baseline: 7.6879x; 7.6879x over previous
//
#include <hip/hip_runtime.h>
#include <math.h>

#define BB 16384      // B
#define CC 50         // clusters
#define KK 128        // top-K
#define DD 128        // feature dim
#define MM 12800      // CC*2*KK rows of F
#define NSPLIT 20     // column splits for sim_all
#define CPS (MM / NSPLIT)       // 640 cols per split
#define TILE_COLS 32
#define TILES_PER_SPLIT (CPS / TILE_COLS)   // 20
#define SCALE2 2.8853900817779268f          // 2/ln2 : exp(x/0.5)=exp2(x*SCALE2)

typedef __bf16 bf16x8 __attribute__((ext_vector_type(8)));
typedef float f32x4 __attribute__((ext_vector_type(4)));

// ---------------- float <-> bf16 (RNE), self-contained ----------------
__device__ inline unsigned short f2bf(float x) {
  unsigned u = __float_as_uint(x);
  unsigned r = (u + 0x7fffu + ((u >> 16) & 1u)) >> 16;
  return (unsigned short)r;
}
__device__ inline float bf2f(unsigned short h) {
  return __uint_as_float(((unsigned)h) << 16);
}

// ---------------------------------------------------------------------------
// Kernel 1: per-cluster top-K via radix select (unchanged from round 1; passed).
// ---------------------------------------------------------------------------
__global__ void topk_kernel(const float* __restrict__ prob, int* __restrict__ topk) {
  __shared__ int hist[256];
  __shared__ int sChosen, sKrem, gtc, eqc;
  __shared__ int eqIdx[256];
  const int c = blockIdx.x, t = threadIdx.x;
  unsigned prefix = 0;
  int k_rem = KK;
  for (int pass = 0; pass < 4; ++pass) {
    const int shift = 24 - pass * 8;
    hist[t] = 0;
    __syncthreads();
    for (int i = t; i < BB; i += 256) {
      unsigned u = __float_as_uint(prob[i * CC + c]);
      bool match = (pass == 0) || ((u >> (shift + 8)) == (prefix >> (shift + 8)));
      if (match) atomicAdd(&hist[(u >> shift) & 255], 1);
    }
    __syncthreads();
    if (t == 0) {
      int kr = k_rem, b = 255;
      for (; b > 0; --b) {
        if (kr > hist[b]) kr -= hist[b];
        else break;
      }
      sChosen = b; sKrem = kr;
    }
    __syncthreads();
    prefix |= ((unsigned)sChosen) << shift;
    k_rem = sKrem;
    __syncthreads();
  }
  const unsigned T = prefix;
  if (t == 0) { gtc = 0; eqc = 0; }
  __syncthreads();
  for (int i = t; i < BB; i += 256) {
    unsigned u = __float_as_uint(prob[i * CC + c]);
    if (u > T) {
      int pos = atomicAdd(&gtc, 1);
      topk[c * KK + pos] = i;
    } else if (u == T) {
      int e = atomicAdd(&eqc, 1);
      if (e < 256) eqIdx[e] = i;
    }
  }
  __syncthreads();
  if (t == 0) {
    int base = gtc;
    int ec = eqc < 256 ? eqc : 256;
    for (int j = 0; j < k_rem; ++j) {
      int bi = -1, bv = 0x7fffffff;
      for (int q = 0; q < ec; ++q) {
        int v = eqIdx[q];
        if (v >= 0 && v < bv) { bv = v; bi = q; }
      }
      topk[c * KK + base + j] = bv;
      eqIdx[bi] = -1;
    }
  }
}

// ---------------------------------------------------------------------------
// Kernel 2: gather + L2-normalize + hi/lo bf16 split. One wave per row.
// ---------------------------------------------------------------------------
__global__ void gather_norm(const float* __restrict__ zi, const float* __restrict__ zj,
                            const int* __restrict__ topk,
                            unsigned short* __restrict__ Fhi,
                            unsigned short* __restrict__ Flo) {
  const int gw = (blockIdx.x * 256 + threadIdx.x) >> 6;
  const int lane = threadIdx.x & 63;
  if (gw >= MM) return;
  const int c = gw >> 8, p = gw & 255;
  const int idx = topk[c * KK + (p & (KK - 1))];
  const float* src = (p < KK ? zi : zj) + (size_t)idx * DD;
  float2 v = ((const float2*)src)[lane];
  float ss = fmaf(v.x, v.x, v.y * v.y);
#pragma unroll
  for (int m = 1; m < 64; m <<= 1) ss += __shfl_xor(ss, m, 64);
  const float scale = 1.0f / fmaxf(sqrtf(ss), 1e-8f);
  float a = v.x * scale, b = v.y * scale;
  unsigned short ah = f2bf(a), bh = f2bf(b);
  unsigned short al = f2bf(a - bf2f(ah)), bl = f2bf(b - bf2f(bh));
  unsigned hp = ((unsigned)bh << 16) | ah;
  unsigned lp = ((unsigned)bl << 16) | al;
  *(unsigned*)((char*)Fhi + ((size_t)gw << 8) + lane * 4) = hp;
  *(unsigned*)((char*)Flo + ((size_t)gw << 8) + lane * 4) = lp;
}

// ---------------------------------------------------------------------------
// Kernel 3: sum_all. Block = 4 waves x 64 rows = 256 rows (one cluster),
// cols = one split (640) in 32-col LDS tiles. A (hi+lo) lives in registers.
// LDS layout (per hi/lo tile, 8 KB): byte = col*256 + ((j ^ (col&7))<<4),
// j = 16B-granule index within the row of 128 bf16. Swizzle applied on both
// write and read (rule 21). 3-product Ootomo accumulate, exp2 epilogue.
// ---------------------------------------------------------------------------
__global__ __launch_bounds__(256, 2) void sim_all_kernel(
    const unsigned short* __restrict__ Fhi, const unsigned short* __restrict__ Flo,
    float* __restrict__ part) {
  __shared__ __align__(16) char Bs[16384];   // [0,8K)=hi tile, [8K,16K)=lo tile
  const int tid = threadIdx.x;
  const int lane = tid & 63, wave = tid >> 6;
  const int c = blockIdx.x / NSPLIT, split = blockIdx.x - c * NSPLIT;
  const int rowW = c * 256 + wave * 64;
  const int colBase = split * CPS;
  const int l15 = lane & 15, lh = lane >> 4, s = l15 & 7;

  // ---- A fragments in registers: 64 rows x 128 K, hi+lo ----
  bf16x8 Ahi[4][4], Alo[4][4];
#pragma unroll
  for (int rg = 0; rg < 4; ++rg)
#pragma unroll
    for (int kc = 0; kc < 4; ++kc) {
      size_t off = ((size_t)(rowW + rg * 16 + l15) << 7) + kc * 32 + lh * 8;
      Ahi[rg][kc] = *(const bf16x8*)(Fhi + off);
      Alo[rg][kc] = *(const bf16x8*)(Flo + off);
    }

  // ---- staging geometry: this thread's two 16B granules ----
  const int g0 = tid, g1 = tid + 256;
  const int c0_ = g0 >> 4, j0 = g0 & 15;
  const int c1_ = g1 >> 4, j1 = g1 & 15;
  const int w0 = c0_ * 256 + ((j0 ^ (c0_ & 7)) << 4);
  const int w1 = c1_ * 256 + ((j1 ^ (c1_ & 7)) << 4);

  float4 s0h, s1h, s0l, s1l;
  auto LOAD_TILE = [&](int colT) {
    const char* ph = (const char*)Fhi;
    const char* pl = (const char*)Flo;
    s0h = *(const float4*)(ph + ((size_t)(colT + c0_) << 8) + (j0 << 4));
    s1h = *(const float4*)(ph + ((size_t)(colT + c1_) << 8) + (j1 << 4));
    s0l = *(const float4*)(pl + ((size_t)(colT + c0_) << 8) + (j0 << 4));
    s1l = *(const float4*)(pl + ((size_t)(colT + c1_) << 8) + (j1 << 4));
  };

  float sAll[16] = {0.f};
  LOAD_TILE(colBase);

  for (int t = 0; t < TILES_PER_SPLIT; ++t) {
    __syncthreads();                       // previous tile's readers done
    *(float4*)(Bs + w0) = s0h;
    *(float4*)(Bs + w1) = s1h;
    *(float4*)(Bs + 8192 + w0) = s0l;
    *(float4*)(Bs + 8192 + w1) = s1l;
    if (t + 1 < TILES_PER_SPLIT) LOAD_TILE(colBase + (t + 1) * TILE_COLS);  // T14: issue early
    __syncthreads();                       // tile ready

    f32x4 acc[4][2] = {};
#pragma unroll
    for (int kc = 0; kc < 4; ++kc)
#pragma unroll
      for (int cg = 0; cg < 2; ++cg) {
        const int rb = ((cg * 16 + l15) << 8) + ((((kc << 2) + lh) ^ s) << 4);
        bf16x8 bhi = *(const bf16x8*)(Bs + rb);
        bf16x8 blo = *(const bf16x8*)(Bs + 8192 + rb);
#pragma unroll
        for (int rg = 0; rg < 4; ++rg)
          acc[rg][cg] = __builtin_amdgcn_mfma_f32_16x16x32_bf16(Ahi[rg][kc], bhi, acc[rg][cg], 0, 0, 0);
#pragma unroll
        for (int rg = 0; rg < 4; ++rg)
          acc[rg][cg] = __builtin_amdgcn_mfma_f32_16x16x32_bf16(Ahi[rg][kc], blo, acc[rg][cg], 0, 0, 0);
#pragma unroll
        for (int rg = 0; rg < 4; ++rg)
          acc[rg][cg] = __builtin_amdgcn_mfma_f32_16x16x32_bf16(Alo[rg][kc], bhi, acc[rg][cg], 0, 0, 0);
      }
#pragma unroll
    for (int rg = 0; rg < 4; ++rg)
#pragma unroll
      for (int i = 0; i < 4; ++i)
        sAll[rg * 4 + i] += __builtin_amdgcn_exp2f(acc[rg][0][i] * SCALE2) +
                            __builtin_amdgcn_exp2f(acc[rg][1][i] * SCALE2);
  }

  // reduce across the 16 column-lanes
#pragma unroll
  for (int m = 1; m < 16; m <<= 1)
#pragma unroll
    for (int j = 0; j < 16; ++j) sAll[j] += __shfl_xor(sAll[j], m, 16);
  if (l15 == 0) {
#pragma unroll
    for (int rg = 0; rg < 4; ++rg)
#pragma unroll
      for (int i = 0; i < 4; ++i) {
        int row = rowW + rg * 16 + lh * 4 + i;
        part[(size_t)row * NSPLIT + split] = sAll[rg * 4 + i];
      }
  }
}

// ---------------------------------------------------------------------------
// Kernel 4: own-block sums. 200 blocks = (cluster, quarter); wave owns 16 rows;
// cols = the cluster's 256 in 8 tiles. Outputs own_sum, pos_sum per row.
// ---------------------------------------------------------------------------
__global__ __launch_bounds__(256) void own_kernel(
    const unsigned short* __restrict__ Fhi, const unsigned short* __restrict__ Flo,
    float* __restrict__ ownArr, float* __restrict__ posArr) {
  __shared__ __align__(16) char Bs[16384];
  const int tid = threadIdx.x;
  const int lane = tid & 63, wave = tid >> 6;
  const int c = blockIdx.x >> 2, q = blockIdx.x & 3;
  const int rowW = c * 256 + q * 64 + wave * 16;
  const int colBase = c * 256;
  const int l15 = lane & 15, lh = lane >> 4, s = l15 & 7;

  bf16x8 Ahi[4], Alo[4];
#pragma unroll
  for (int kc = 0; kc < 4; ++kc) {
    size_t off = ((size_t)(rowW + l15) << 7) + kc * 32 + lh * 8;
    Ahi[kc] = *(const bf16x8*)(Fhi + off);
    Alo[kc] = *(const bf16x8*)(Flo + off);
  }

  const int g0 = tid, g1 = tid + 256;
  const int c0_ = g0 >> 4, j0 = g0 & 15;
  const int c1_ = g1 >> 4, j1 = g1 & 15;
  const int w0 = c0_ * 256 + ((j0 ^ (c0_ & 7)) << 4);
  const int w1 = c1_ * 256 + ((j1 ^ (c1_ & 7)) << 4);

  float4 s0h, s1h, s0l, s1l;
  auto LOAD_TILE = [&](int colT) {
    const char* ph = (const char*)Fhi;
    const char* pl = (const char*)Flo;
    s0h = *(const float4*)(ph + ((size_t)(colT + c0_) << 8) + (j0 << 4));
    s1h = *(const float4*)(ph + ((size_t)(colT + c1_) << 8) + (j1 << 4));
    s0l = *(const float4*)(pl + ((size_t)(colT + c0_) << 8) + (j0 << 4));
    s1l = *(const float4*)(pl + ((size_t)(colT + c1_) << 8) + (j1 << 4));
  };

  float sOwn[4] = {0.f}, sPos[4] = {0.f};
  LOAD_TILE(colBase);

  for (int t = 0; t < 8; ++t) {
    __syncthreads();
    *(float4*)(Bs + w0) = s0h;
    *(float4*)(Bs + w1) = s1h;
    *(float4*)(Bs + 8192 + w0) = s0l;
    *(float4*)(Bs + 8192 + w1) = s1l;
    if (t + 1 < 8) LOAD_TILE(colBase + (t + 1) * TILE_COLS);
    __syncthreads();

    f32x4 acc[2] = {};
#pragma unroll
    for (int kc = 0; kc < 4; ++kc)
#pragma unroll
      for (int cg = 0; cg < 2; ++cg) {
        const int rb = ((cg * 16 + l15) << 8) + ((((kc << 2) + lh) ^ s) << 4);
        bf16x8 bhi = *(const bf16x8*)(Bs + rb);
        bf16x8 blo = *(const bf16x8*)(Bs + 8192 + rb);
        acc[cg] = __builtin_amdgcn_mfma_f32_16x16x32_bf16(Ahi[kc], bhi, acc[cg], 0, 0, 0);
        acc[cg] = __builtin_amdgcn_mfma_f32_16x16x32_bf16(Ahi[kc], blo, acc[cg], 0, 0, 0);
        acc[cg] = __builtin_amdgcn_mfma_f32_16x16x32_bf16(Alo[kc], bhi, acc[cg], 0, 0, 0);
      }
    const bool isPos = (t < 4);   // first 128 cols of the cluster block
#pragma unroll
    for (int i = 0; i < 4; ++i) {
      float e = __builtin_amdgcn_exp2f(acc[0][i] * SCALE2) +
                __builtin_amdgcn_exp2f(acc[1][i] * SCALE2);
      sOwn[i] += e;
      if (isPos) sPos[i] += e;
    }
  }
#pragma unroll
  for (int m = 1; m < 16; m <<= 1)
#pragma unroll
    for (int i = 0; i < 4; ++i) {
      sOwn[i] += __shfl_xor(sOwn[i], m, 16);
      sPos[i] += __shfl_xor(sPos[i], m, 16);
    }
  if (l15 == 0) {
#pragma unroll
    for (int i = 0; i < 4; ++i) {
      int row = rowW + lh * 4 + i;
      ownArr[row] = sOwn[i];
      posArr[row] = sPos[i];
    }
  }
}

// ---------------------------------------------------------------------------
// Kernel 5: per-row loss
// ---------------------------------------------------------------------------
__global__ void finalize_rows(const float* __restrict__ part,
                              const float* __restrict__ ownArr,
                              const float* __restrict__ posArr,
                              float* __restrict__ row_loss) {
  const int p = blockIdx.x * 256 + threadIdx.x;
  if (p >= MM) return;
  float a = 0.f;
#pragma unroll
  for (int sp = 0; sp < NSPLIT; ++sp) a += part[(size_t)p * NSPLIT + sp];
  row_loss[p] = logf(a - ownArr[p]) - logf(posArr[p]);
}

// ---------------------------------------------------------------------------
// Kernel 6: mean -> scalar
// ---------------------------------------------------------------------------
__global__ void final_reduce(const float* __restrict__ row_loss, float* __restrict__ out) {
  __shared__ float red[16];
  const int t = threadIdx.x;                // 1024 threads
  float ssum = 0.f;
  for (int i = t; i < MM; i += 1024) ssum += row_loss[i];
#pragma unroll
  for (int m = 1; m < 64; m <<= 1) ssum += __shfl_xor(ssum, m, 64);
  if ((t & 63) == 0) red[t >> 6] = ssum;
  __syncthreads();
  if (t < 16) {
    float v = red[t];
#pragma unroll
    for (int m = 1; m < 16; m <<= 1) v += __shfl_xor(v, m, 16);
    if (t == 0) out[0] = v * (1.0f / MM);
  }
}

extern "C" void kernel_launch(void* const* d_in, const int* in_sizes, int n_in,
                              void* d_out, int out_size, void* d_ws, size_t ws_size,
                              hipStream_t stream) {
  const float* prob = (const float*)d_in[0];
  const float* zi   = (const float*)d_in[1];
  const float* zj   = (const float*)d_in[2];
  float* out = (float*)d_out;

  char* ws = (char*)d_ws;
  unsigned short* Fhi = (unsigned short*)(ws);                       // 3,276,800 B
  unsigned short* Flo = (unsigned short*)(ws + 3276800);             // 3,276,800 B
  float* part     = (float*)(ws + 6553600);                          // 1,024,000 B
  float* ownArr   = (float*)(ws + 7577600);                          //    51,200 B
  float* posArr   = (float*)(ws + 7628800);                          //    51,200 B
  float* row_loss = (float*)(ws + 7680000);                          //    51,200 B
  int*   topk     = (int*)  (ws + 7731200);                          //    25,600 B

  topk_kernel   <<<CC, 256, 0, stream>>>(prob, topk);
  gather_norm   <<<MM / 4, 256, 0, stream>>>(zi, zj, topk, Fhi, Flo);
  sim_all_kernel<<<CC * NSPLIT, 256, 0, stream>>>(Fhi, Flo, part);
  own_kernel    <<<CC * 4, 256, 0, stream>>>(Fhi, Flo, ownArr, posArr);
  finalize_rows <<<MM / 256, 256, 0, stream>>>(part, ownArr, posArr, row_loss);
  final_reduce  <<<1, 1024, 0, stream>>>(row_loss, out);
}